// Round 8
// baseline (82.281 us; speedup 1.0000x reference)
//
#include <hip/hip_runtime.h>
#include <hip/hip_bf16.h>

#define M_ROWS 256
#define T_LEN  1024
#define NLAG   2048
#define GSTB   2096   // bytes per shifted fp8 copy; 131 x 16B chunks
#define NCOPY  16
#define TBLW   8384   // u32 words per j in shift table (16*2096/4)

typedef __attribute__((ext_vector_type(4)))  unsigned int u32x4;
typedef __attribute__((ext_vector_type(8)))  int          i32x8;
typedef __attribute__((ext_vector_type(16))) float        f32x16;

static __device__ __forceinline__ unsigned short f2bf(float f) {
  unsigned int u = __builtin_bit_cast(unsigned int, f);
  u += 0x7FFFu + ((u >> 16) & 1u);   // RNE
  return (unsigned short)(u >> 16);
}

// ---------------- prep: center rows, fp8-ify, std(ddof=1), build shift table ----------------
// f1 -> packed fragment bytes f1p8[[kg][h][row][32B]]
// f2 -> gshift[j][cp][x] = fp8(f2c_j)[(x - cp) mod 2048], x in [0,2096)
__global__ __launch_bounds__(256) void prep_kernel(
    const float* __restrict__ zis, const float* __restrict__ zjs,
    unsigned int* __restrict__ f1p8, unsigned int* __restrict__ gshift,
    float* __restrict__ s1, float* __restrict__ s2) {
  int r = blockIdx.x;  // 0..511
  const float* src = (r < M_ROWS) ? (zis + r * T_LEN) : (zjs + (r - M_ROWS) * T_LEN);
  int t = threadIdx.x;
  float4 v = reinterpret_cast<const float4*>(src)[t];
  float ls = v.x + v.y + v.z + v.w;
  for (int m = 1; m <= 32; m <<= 1) ls += __shfl_xor(ls, m, 64);
  __shared__ float red[4];
  __shared__ float red2[4];
  __shared__ unsigned int rowlds[520];   // padded fp8 row: 1024 data | 1024 zero | 32 wrap
  if ((t & 63) == 0) red[t >> 6] = ls;
  __syncthreads();
  float mean = (red[0] + red[1] + red[2] + red[3]) * (1.0f / 1024.0f);
  float c0 = v.x - mean, c1 = v.y - mean, c2 = v.z - mean, c3 = v.w - mean;
  float ss = c0 * c0 + c1 * c1 + c2 * c2 + c3 * c3;
  for (int m = 1; m <= 32; m <<= 1) ss += __shfl_xor(ss, m, 64);
  if ((t & 63) == 0) red2[t >> 6] = ss;
  __syncthreads();
  float sd = sqrtf((red2[0] + red2[1] + red2[2] + red2[3]) * (1.0f / 1023.0f));

  unsigned int w = (unsigned int)__builtin_amdgcn_cvt_pk_fp8_f32(c0, c1, 0, false);
  w = (unsigned int)__builtin_amdgcn_cvt_pk_fp8_f32(c2, c3, (int)w, true);

  if (r < M_ROWS) {
    if (t == 0) s1[r] = sd;
    f1p8[((((t >> 4) * 2 + ((t >> 3) & 1)) * 256 + r) << 3) + (t & 7)] = w;
  } else {
    int j = r - M_ROWS;
    if (t == 0) s2[j] = sd;
    rowlds[t] = w;
    rowlds[256 + t] = 0u;
    if (t < 8) rowlds[512 + t] = w;
    __syncthreads();
    unsigned int* dst = gshift + j * TBLW;
#pragma unroll
    for (int m = 0; m < 9; ++m) {
      int ch = m * 256 + t;
      if (ch < 2096) {
        int cp = ch / 131;            // compile-time magic-mul
        int cc = ch - cp * 131;
        int base = ((cc << 4) - cp) & (NLAG - 1);
        int wb = base >> 2;
        int sh = (base & 3) << 3;
        unsigned int w0 = rowlds[wb], w1 = rowlds[wb + 1], w2 = rowlds[wb + 2],
                     w3 = rowlds[wb + 3], w4 = rowlds[wb + 4];
        u32x4 o;
        if (sh) {
          o[0] = (w0 >> sh) | (w1 << (32 - sh));
          o[1] = (w1 >> sh) | (w2 << (32 - sh));
          o[2] = (w2 >> sh) | (w3 << (32 - sh));
          o[3] = (w3 >> sh) | (w4 << (32 - sh));
        } else {
          o[0] = w0; o[1] = w1; o[2] = w2; o[3] = w3;
        }
        *reinterpret_cast<u32x4*>(dst + ch * 4) = o;
      }
    }
  }
}

#define MK8(LO, HI) \
  (i32x8){(int)(LO)[0], (int)(LO)[1], (int)(LO)[2], (int)(LO)[3], \
          (int)(HI)[0], (int)(HI)[1], (int)(HI)[2], (int)(HI)[3]}

#define LOADF(F0L, F0H, F1L, F1H)            \
  {                                          \
    F0L = *(const u32x4*)(fp);               \
    F0H = *(const u32x4*)(fp + 4);           \
    F1L = *(const u32x4*)(fp + 256);         \
    F1H = *(const u32x4*)(fp + 260);         \
    fp += 4096;                              \
  }

// one K=64 step: G (lags) from LDS just-in-time, F (rows) from pipelined regs; 4 scaled MFMA
#define STEP(F0L, F0H, F1L, F1H, KS)                                                     \
  {                                                                                      \
    int x0 = (((KS) << 6) + cst0) & (NLAG - 1);                                          \
    int x1 = (((KS) << 6) + cst1) & (NLAG - 1);                                          \
    u32x4 g0l = *(const u32x4*)(gbase + x0);                                             \
    u32x4 g0h = *(const u32x4*)(gbase + x0 + 16);                                        \
    u32x4 g1l = *(const u32x4*)(gbase + x1);                                             \
    u32x4 g1h = *(const u32x4*)(gbase + x1 + 16);                                        \
    i32x8 G0 = MK8(g0l, g0h);                                                            \
    i32x8 G1 = MK8(g1l, g1h);                                                            \
    i32x8 F0 = MK8(F0L, F0H);                                                            \
    i32x8 F1 = MK8(F1L, F1H);                                                            \
    z00 = __builtin_amdgcn_mfma_scale_f32_32x32x64_f8f6f4(G0, F0, z00, 0, 0, 0, 127, 0, 127); \
    z01 = __builtin_amdgcn_mfma_scale_f32_32x32x64_f8f6f4(G0, F1, z01, 0, 0, 0, 127, 0, 127); \
    z10 = __builtin_amdgcn_mfma_scale_f32_32x32x64_f8f6f4(G1, F0, z10, 0, 0, 0, 127, 0, 127); \
    z11 = __builtin_amdgcn_mfma_scale_f32_32x32x64_f8f6f4(G1, F1, z11, 0, 0, 0, 127, 0, 127); \
  }

// ---------------- Toeplitz-GEMM correlation (MX-fp8, swapped operands) ----------------
// grid: wg = blk*256 + j ; 4096 wgs, 512 threads = 8 waves.
// wave w: rows (w&3)*64 .. +63 (as MFMA-B), lags tau0 + (w>>2)*64 .. +63 (as MFMA-A).
__global__ __launch_bounds__(512, 4) void corr_kernel(
    const unsigned int* __restrict__ f1p8,
    const unsigned int* __restrict__ gshift,
    unsigned short* __restrict__ part) {
  __shared__ __align__(16) unsigned char ldsB[NCOPY * GSTB];  // 33536 B
  __shared__ float red[2][256];

  int wg = blockIdx.x;
  int j = wg & 255;
  int blk = wg >> 8;        // 0..15
  int tau0 = blk << 7;

  int tid = threadIdx.x;
  int lane = tid & 63;
  int w = tid >> 6;
  int rw = w & 3;           // row quarter
  int lh = w >> 2;          // lag half (64-lag granule)
  int l5 = lane >> 5;
  int l31 = lane & 31;

  // ---- stage the premade 16-copy shift table: pure linear global->LDS (262 chunks/wave) ----
  {
    const unsigned int* gj = gshift + j * TBLW;
    auto lds3 = (__attribute__((address_space(3))) unsigned char*)(ldsB);
    int chb = w * 262;
#pragma unroll
    for (int i = 0; i < 4; ++i) {
      int ch = chb + i * 64 + lane;
      __builtin_amdgcn_global_load_lds(
          (const __attribute__((address_space(1))) unsigned int*)(gj + ch * 4),
          (__attribute__((address_space(3))) unsigned int*)(lds3 + (chb + i * 64) * 16),
          16, 0, 0);
    }
    if (lane < 6) {
      int ch = chb + 256 + lane;
      __builtin_amdgcn_global_load_lds(
          (const __attribute__((address_space(1))) unsigned int*)(gj + ch * 4),
          (__attribute__((address_space(3))) unsigned int*)(lds3 + (chb + 256) * 16),
          16, 0, 0);
    }
  }
  asm volatile("s_waitcnt vmcnt(0)" ::: "memory");
  __syncthreads();

  // k64-step range for this 128-lag block
  int kA, kB;
  if (tau0 < 1024) { kA = tau0 >> 6; kB = 16; }
  else             { kA = 0;         kB = ((tau0 - 898) >> 6) + 1; }
  // kB - kA is even and >= 2

  // F (rows, MFMA-B operand): u32 index ((ks*2 + l5)*256 + row)*8
  const unsigned int* fp = f1p8 + ((((kA * 2 + l5) * 256) + rw * 64 + l31) << 3);
  // G (lags, MFMA-A operand): copy rB = lag mod 16, 16B-aligned offset within copy
  int rB = l31 & 15;
  const unsigned char* gbase = ldsB + rB * GSTB;
  int cst0 = 32 * l5 - tau0 - 32 * (2 * lh) - ((l31 >> 4) << 4);
  int cst1 = cst0 - 32;

  f32x16 z00, z01, z10, z11;  // z[lag-frag][row-frag]
#pragma unroll
  for (int q = 0; q < 16; ++q) { z00[q] = 0.f; z01[q] = 0.f; z10[q] = 0.f; z11[q] = 0.f; }

  u32x4 xf0l, xf0h, xf1l, xf1h, yf0l, yf0h, yf1l, yf1h;
  LOADF(xf0l, xf0h, xf1l, xf1h);
  int ks = kA;
#pragma unroll 1
  for (; ks + 2 < kB; ks += 2) {
    LOADF(yf0l, yf0h, yf1l, yf1h);
    STEP(xf0l, xf0h, xf1l, xf1h, ks);
    LOADF(xf0l, xf0h, xf1l, xf1h);
    STEP(yf0l, yf0h, yf1l, yf1h, ks + 1);
  }
  LOADF(yf0l, yf0h, yf1l, yf1h);
  STEP(xf0l, xf0h, xf1l, xf1h, ks);
  STEP(yf0l, yf0h, yf1l, yf1h, ks + 1);

  // ---- per-row max: lags are lane-local (swap trick) -> in-register fold + 1 shuffle ----
  float a0 = fmaxf(z00[0], z10[0]);
  float a1 = fmaxf(z01[0], z11[0]);
#pragma unroll
  for (int q = 1; q < 16; ++q) {
    a0 = fmaxf(a0, fmaxf(z00[q], z10[q]));
    a1 = fmaxf(a1, fmaxf(z01[q], z11[q]));
  }
  a0 = fmaxf(a0, __shfl_xor(a0, 32, 64));
  a1 = fmaxf(a1, __shfl_xor(a1, 32, 64));
  if (l5 == 0) {
    red[lh][rw * 64 + l31] = a0;        // rows rw*64 + 0..31
    red[lh][rw * 64 + 32 + l31] = a1;   // rows rw*64 + 32..63
  }
  __syncthreads();
  if (tid < 256)
    part[(tid * 16 + blk) * 256 + j] = f2bf(fmaxf(red[0][tid], red[1][tid]));
}

// ---------------- per-row CE: dist, logsumexp, pick target ----------------
__global__ __launch_bounds__(256) void loss_kernel(
    const unsigned short* __restrict__ part, const float* __restrict__ s1,
    const float* __restrict__ s2, const int* __restrict__ speeds,
    float* __restrict__ lossrows) {
  int i = blockIdx.x;
  int jt = threadIdx.x;
  unsigned short um = part[(i * 16 + 0) * 256 + jt];
  float m = __builtin_bit_cast(float, ((unsigned int)um) << 16);
#pragma unroll
  for (int b = 1; b < 16; ++b) {
    unsigned short ub = part[(i * 16 + b) * 256 + jt];
    m = fmaxf(m, __builtin_bit_cast(float, ((unsigned int)ub) << 16));
  }
  float p = s1[i] * s2[jt];
  p = (p == 0.0f) ? 1.0f : p;
  float d = m / (p * 1023.0f);

  float t = d;
  for (int mk = 1; mk <= 32; mk <<= 1) t = fmaxf(t, __shfl_xor(t, mk, 64));
  __shared__ float wmax[4], wsum[4], sel;
  if ((jt & 63) == 0) wmax[jt >> 6] = t;
  if (jt == speeds[i]) sel = d;
  __syncthreads();
  float rmax = fmaxf(fmaxf(wmax[0], wmax[1]), fmaxf(wmax[2], wmax[3]));
  float e = expf(d - rmax);
  for (int mk = 1; mk <= 32; mk <<= 1) e += __shfl_xor(e, mk, 64);
  if ((jt & 63) == 0) wsum[jt >> 6] = e;
  __syncthreads();
  if (jt == 0) {
    float sum = wsum[0] + wsum[1] + wsum[2] + wsum[3];
    lossrows[i] = rmax + logf(sum) - sel;
  }
}

__global__ __launch_bounds__(256) void sum_kernel(const float* __restrict__ lossrows,
                                                  float* __restrict__ out) {
  int t = threadIdx.x;
  float v = lossrows[t];
  for (int mk = 1; mk <= 32; mk <<= 1) v += __shfl_xor(v, mk, 64);
  __shared__ float wsh[4];
  if ((t & 63) == 0) wsh[t >> 6] = v;
  __syncthreads();
  if (t == 0) out[0] = wsh[0] + wsh[1] + wsh[2] + wsh[3];
}

extern "C" void kernel_launch(void* const* d_in, const int* in_sizes, int n_in,
                              void* d_out, int out_size, void* d_ws, size_t ws_size,
                              hipStream_t stream) {
  (void)in_sizes; (void)n_in; (void)out_size; (void)ws_size;
  const float* zis = (const float*)d_in[0];
  const float* zjs = (const float*)d_in[1];
  const int* speeds = (const int*)d_in[2];
  float* out = (float*)d_out;

  char* ws = (char*)d_ws;
  unsigned int* f1p8 = (unsigned int*)ws;                          // 256 KB packed fp8 A
  unsigned int* gshift = (unsigned int*)(ws + 262144);             // 8.59 MB shift table
  float* s1 = (float*)(ws + 8847360);                              // 1 KB
  float* s2 = (float*)(ws + 8848384);                              // 1 KB
  unsigned short* part = (unsigned short*)(ws + 8849408);          // 2 MB bf16 [i][blk][j]
  float* lossrows = (float*)(ws + 8849408 + 2097152);              // 1 KB

  prep_kernel<<<512, 256, 0, stream>>>(zis, zjs, f1p8, gshift, s1, s2);
  corr_kernel<<<4096, 512, 0, stream>>>(f1p8, gshift, part);
  loss_kernel<<<256, 256, 0, stream>>>(part, s1, s2, speeds, lossrows);
  sum_kernel<<<1, 256, 0, stream>>>(lossrows, out);
}